// Round 5
// baseline (14081.049 us; speedup 1.0000x reference)
//
#include <hip/hip_runtime.h>
#include <math.h>

// Problem constants (Elman RNN)
#define TT 4096
#define HH 2048
#define OO 512

#define NB  64    // scan blocks
#define RPB 32    // rows per block = HH/NB

// ---------------------------------------------------------------------------
// Phase 1 & 3: fp32 NT GEMM  C[m,n] = sum_k A[m,k]*B[n,k] + bias[n]
// 128x128 tile, 256 threads, 8x8 per thread, BK=8. (unchanged)
// ---------------------------------------------------------------------------
__global__ __launch_bounds__(256) void gemm_nt_bias(
    const float* __restrict__ A, const float* __restrict__ B,
    const float* __restrict__ bias, float* __restrict__ C,
    int M, int N, int K)
{
    __shared__ float As[8][128];
    __shared__ float Bs[8][128];

    const int tid = threadIdx.x;
    const int bm = blockIdx.x * 128;
    const int bn = blockIdx.y * 128;

    const int lrow = tid >> 1;
    const int lk   = (tid & 1) * 4;

    const int ty = tid >> 4;
    const int tx = tid & 15;

    float acc[8][8];
#pragma unroll
    for (int i = 0; i < 8; i++)
#pragma unroll
        for (int j = 0; j < 8; j++) acc[i][j] = 0.f;

    for (int k0 = 0; k0 < K; k0 += 8) {
        float4 av = *(const float4*)&A[(size_t)(bm + lrow) * K + k0 + lk];
        float4 bv = *(const float4*)&B[(size_t)(bn + lrow) * K + k0 + lk];
        __syncthreads();
        As[lk + 0][lrow] = av.x; As[lk + 1][lrow] = av.y;
        As[lk + 2][lrow] = av.z; As[lk + 3][lrow] = av.w;
        Bs[lk + 0][lrow] = bv.x; Bs[lk + 1][lrow] = bv.y;
        Bs[lk + 2][lrow] = bv.z; Bs[lk + 3][lrow] = bv.w;
        __syncthreads();
#pragma unroll
        for (int kk = 0; kk < 8; kk++) {
            float a[8], b[8];
            *(float4*)&a[0] = *(const float4*)&As[kk][ty * 4];
            *(float4*)&a[4] = *(const float4*)&As[kk][64 + ty * 4];
            *(float4*)&b[0] = *(const float4*)&Bs[kk][tx * 4];
            *(float4*)&b[4] = *(const float4*)&Bs[kk][64 + tx * 4];
#pragma unroll
            for (int i = 0; i < 8; i++)
#pragma unroll
                for (int j = 0; j < 8; j++)
                    acc[i][j] += a[i] * b[j];
        }
    }

#pragma unroll
    for (int g = 0; g < 2; g++) {
        const int n = bn + g * 64 + tx * 4;
        float4 bv = *(const float4*)&bias[n];
#pragma unroll
        for (int i = 0; i < 8; i++) {
            const int m = bm + ((i < 4) ? (ty * 4 + i) : (64 + ty * 4 + (i - 4)));
            float4 cv;
            cv.x = acc[i][g * 4 + 0] + bv.x;
            cv.y = acc[i][g * 4 + 1] + bv.y;
            cv.z = acc[i][g * 4 + 2] + bv.z;
            cv.w = acc[i][g * 4 + 3] + bv.w;
            *(float4*)&C[(size_t)m * N + n] = cv;
        }
    }
}

// ---------------------------------------------------------------------------
// Phase 2: persistent scan, 64 blocks x 1024 threads, block owns 32 rows.
//
// R5 changes (vs R4):
//  (a) combined poll loop: both mailbox words issued back-to-back each
//      retry -> one fabric RT covers both (R4 retried them serially).
//  (b) shfl_xor(p,32) merges the two 64-k sub-halves in-register:
//      partial fan 32 -> 16 per row, partial LDS writes halve.
//  (c) final reduce parallelized: 512 threads (8 waves) read 1 partial
//      each, 4-level 16-lane shuffle tree, 32 rows tanh+publish in
//      parallel (R4: one wave serially read 32 partials per row).
//  Weights stay pinned via atomic-load trick (they live in AGPRs --
//  VGPR_Count=52 but no per-step re-streaming, per R4 arithmetic).
// ---------------------------------------------------------------------------
__global__ __launch_bounds__(1024, 4) void rnn_scan(
    const float* __restrict__ xp,    // (T,H) input projection incl. b_ih
    const float* __restrict__ Whh,   // (H,H)
    const float* __restrict__ bhh,   // (H)
    const float* __restrict__ h0,    // (H)
    float* __restrict__ outs,        // (T,H) hidden states out
    unsigned long long* __restrict__ mbox)  // [2][HH] tagged-h mailbox
{
    const int b    = blockIdx.x;     // 0..63
    const int tid  = threadIdx.x;    // 0..1023
    const int wave = tid >> 6;       // 0..15
    const int lane = tid & 63;
    const int r    = lane & 31;      // local row 0..31
    const int row  = b * RPB + r;    // global row this thread accumulates
    const int k0   = wave * 128 + (lane >> 5) * 64;  // k-chunk start

    // weights pinned (atomic loads can't be rematerialized into the loop)
    float w[64];
#pragma unroll
    for (int j = 0; j < 64; ++j)
        w[j] = __hip_atomic_load(&Whh[(size_t)row * HH + k0 + j],
                                 __ATOMIC_RELAXED, __HIP_MEMORY_SCOPE_WORKGROUP);

    // writer threads: tid < 512 && (tid&15)==0 -> one per row, spread over 8 waves
    const bool is_writer = (tid < 512) && ((tid & 15) == 0);
    const int  wrow = tid >> 4;                 // 0..31 (valid when tid<512)
    const int  grow = b * RPB + wrow;
    const float bias = is_writer ? bhh[grow] : 0.f;

    __shared__ float hs[HH];              // staged h (8 KB)
    __shared__ float partial[16][33];     // [k-chunk wave][row], padded

    const int i0 = tid * 2, i1 = tid * 2 + 1;

    for (int t = 0; t < TT; ++t) {
        // xp load: independent of h, issue before the poll
        float xpv = is_writer ? xp[(size_t)t * HH + grow] : 0.f;

        if (t == 0) {
            hs[i0] = h0[i0];
            hs[i1] = h0[i1];
        } else {
            const unsigned int want = (unsigned int)t;
            const unsigned long long* mb = mbox + (size_t)(t & 1) * HH;
            unsigned long long v0, v1;
            do {
                v0 = __hip_atomic_load(&mb[i0],
                    __ATOMIC_RELAXED, __HIP_MEMORY_SCOPE_AGENT);
                v1 = __hip_atomic_load(&mb[i1],
                    __ATOMIC_RELAXED, __HIP_MEMORY_SCOPE_AGENT);
            } while ((((unsigned int)(v0 >> 32)) != want) |
                     (((unsigned int)(v1 >> 32)) != want));
            hs[i0] = __uint_as_float((unsigned int)v0);
            hs[i1] = __uint_as_float((unsigned int)v1);
        }
        __syncthreads();   // (A) staging complete

        // matvec partial: 16 broadcast ds_read_b128 + 64 FMA
        const float* hk = &hs[k0];
        float p = 0.f;
#pragma unroll
        for (int jj = 0; jj < 16; ++jj) {
            float4 h4 = *(const float4*)&hk[jj * 4];
            p += w[jj * 4 + 0] * h4.x + w[jj * 4 + 1] * h4.y
               + w[jj * 4 + 2] * h4.z + w[jj * 4 + 3] * h4.w;
        }
        // merge the two 64-k sub-halves of this wave (full 128-k chunk)
        p += __shfl_xor(p, 32, 64);
        if (lane < 32) partial[wave][lane] = p;
        __syncthreads();   // (B) partials visible; hs reads done

        // parallel reduce: 512 threads, one partial each, 16-lane tree
        if (tid < 512) {
            float s = partial[tid & 15][wrow];
            s += __shfl_xor(s, 8, 64);
            s += __shfl_xor(s, 4, 64);
            s += __shfl_xor(s, 2, 64);
            s += __shfl_xor(s, 1, 64);
            if ((tid & 15) == 0) {
                float hv = tanhf(xpv + bias + s);
                outs[(size_t)t * HH + grow] = hv;   // plain cached store
                unsigned long long pk =
                    ((unsigned long long)(unsigned int)(t + 1) << 32) |
                    (unsigned long long)__float_as_uint(hv);
                __hip_atomic_store(&mbox[(size_t)((t + 1) & 1) * HH + grow], pk,
                                   __ATOMIC_RELAXED, __HIP_MEMORY_SCOPE_AGENT);
            }
        }
        // no step-end barrier: partial[] for t+1 is only written after
        // barrier (A) of t+1, which waits for these reducers.
    }
}

// ---------------------------------------------------------------------------
extern "C" void kernel_launch(void* const* d_in, const int* in_sizes, int n_in,
                              void* d_out, int out_size, void* d_ws, size_t ws_size,
                              hipStream_t stream)
{
    const float* x     = (const float*)d_in[0];  // (T,1,H)
    const float* W_ih  = (const float*)d_in[1];  // (H,H)
    const float* W_hh  = (const float*)d_in[2];  // (H,H)
    const float* b_ih  = (const float*)d_in[3];  // (H)
    const float* b_hh  = (const float*)d_in[4];  // (H)
    const float* W_lin = (const float*)d_in[5];  // (O,H)
    const float* b_lin = (const float*)d_in[6];  // (O)
    const float* h0    = (const float*)d_in[7];  // (1,1,H)
    float* out = (float*)d_out;                  // (T,1,O)

    char* ws = (char*)d_ws;
    float* xp    = (float*)ws;                                       // 32 MB
    float* outs  = (float*)(ws + (size_t)TT * HH * 4);               // 32 MB
    unsigned long long* mbox =
        (unsigned long long*)(ws + 2 * (size_t)TT * HH * 4);         // 32 KB

    // no mailbox init needed: t==0 reads h0 directly; poisoned tag
    // 0xAAAAAAAA never equals a wanted tag (t < 4096).

    // Phase 1: xp = x @ W_ih^T + b_ih
    gemm_nt_bias<<<dim3(TT / 128, HH / 128), 256, 0, stream>>>(
        x, W_ih, b_ih, xp, TT, HH, HH);

    // Phase 2: sequential scan (persistent, 64 co-resident blocks)
    rnn_scan<<<NB, 1024, 0, stream>>>(xp, W_hh, b_hh, h0, outs, mbox);

    // Phase 3: out = outs @ W_lin^T + b_lin
    gemm_nt_bias<<<dim3(TT / 128, OO / 128), 256, 0, stream>>>(
        outs, W_lin, b_lin, out, TT, OO, HH);
}

// Round 6
// 8467.068 us; speedup vs baseline: 1.6630x; 1.6630x over previous
//
#include <hip/hip_runtime.h>
#include <math.h>

// Problem constants (Elman RNN)
#define TT 4096
#define HH 2048
#define OO 512

#define NB  64    // scan blocks
#define RPB 32    // rows per block = HH/NB

// ---------------------------------------------------------------------------
// Phase 1 & 3: fp32 NT GEMM  C[m,n] = sum_k A[m,k]*B[n,k] + bias[n]
// 128x128 tile, 256 threads, 8x8 per thread, BK=8. (unchanged)
// ---------------------------------------------------------------------------
__global__ __launch_bounds__(256) void gemm_nt_bias(
    const float* __restrict__ A, const float* __restrict__ B,
    const float* __restrict__ bias, float* __restrict__ C,
    int M, int N, int K)
{
    __shared__ float As[8][128];
    __shared__ float Bs[8][128];

    const int tid = threadIdx.x;
    const int bm = blockIdx.x * 128;
    const int bn = blockIdx.y * 128;

    const int lrow = tid >> 1;
    const int lk   = (tid & 1) * 4;

    const int ty = tid >> 4;
    const int tx = tid & 15;

    float acc[8][8];
#pragma unroll
    for (int i = 0; i < 8; i++)
#pragma unroll
        for (int j = 0; j < 8; j++) acc[i][j] = 0.f;

    for (int k0 = 0; k0 < K; k0 += 8) {
        float4 av = *(const float4*)&A[(size_t)(bm + lrow) * K + k0 + lk];
        float4 bv = *(const float4*)&B[(size_t)(bn + lrow) * K + k0 + lk];
        __syncthreads();
        As[lk + 0][lrow] = av.x; As[lk + 1][lrow] = av.y;
        As[lk + 2][lrow] = av.z; As[lk + 3][lrow] = av.w;
        Bs[lk + 0][lrow] = bv.x; Bs[lk + 1][lrow] = bv.y;
        Bs[lk + 2][lrow] = bv.z; Bs[lk + 3][lrow] = bv.w;
        __syncthreads();
#pragma unroll
        for (int kk = 0; kk < 8; kk++) {
            float a[8], b[8];
            *(float4*)&a[0] = *(const float4*)&As[kk][ty * 4];
            *(float4*)&a[4] = *(const float4*)&As[kk][64 + ty * 4];
            *(float4*)&b[0] = *(const float4*)&Bs[kk][tx * 4];
            *(float4*)&b[4] = *(const float4*)&Bs[kk][64 + tx * 4];
#pragma unroll
            for (int i = 0; i < 8; i++)
#pragma unroll
                for (int j = 0; j < 8; j++)
                    acc[i][j] += a[i] * b[j];
        }
    }

#pragma unroll
    for (int g = 0; g < 2; g++) {
        const int n = bn + g * 64 + tx * 4;
        float4 bv = *(const float4*)&bias[n];
#pragma unroll
        for (int i = 0; i < 8; i++) {
            const int m = bm + ((i < 4) ? (ty * 4 + i) : (64 + ty * 4 + (i - 4)));
            float4 cv;
            cv.x = acc[i][g * 4 + 0] + bv.x;
            cv.y = acc[i][g * 4 + 1] + bv.y;
            cv.z = acc[i][g * 4 + 2] + bv.z;
            cv.w = acc[i][g * 4 + 3] + bv.w;
            *(float4*)&C[(size_t)m * N + n] = cv;
        }
    }
}

// ---------------------------------------------------------------------------
// Phase 2: persistent scan, 64 blocks x 1024 threads, block owns 32 rows.
//
// R6 (post-R5-regression):
//  * REVERT publish to R4's single-instruction form: wave 0, lanes 0-31,
//    one 256B contiguous store of 32 tagged words. (R5's 8-wave spread
//    publish caused partial-line poll retries: FETCH +173MB, +1.1us/step.)
//  * Wave-PRIVATE staging: wave w only ever reads hs[w*128..w*128+128),
//    so each wave polls its own 128 mailbox words (2/lane) and writes its
//    own LDS chunk -- same-wave dependency, NO block barrier. Barriers
//    per step: 2 -> 1 (only before the reduce).
//  * Reduce: wave 0, 8 conflict-free serial LDS reads/lane over padded
//    partial[16][33] + shfl_xor(32) merge + tanh + publish.
//  Safety (1 barrier): block X publishes t+1 only after ALL its waves
//  read tag t (barrier B + partial deps); any block publishes t+2 only
//  after polling t+1 from all blocks => no tag-t reader overwritten.
// ---------------------------------------------------------------------------
__global__ __launch_bounds__(1024, 4) void rnn_scan(
    const float* __restrict__ xp,    // (T,H) input projection incl. b_ih
    const float* __restrict__ Whh,   // (H,H)
    const float* __restrict__ bhh,   // (H)
    const float* __restrict__ h0,    // (H)
    float* __restrict__ outs,        // (T,H) hidden states out
    unsigned long long* __restrict__ mbox)  // [2][HH] tagged-h mailbox
{
    const int b    = blockIdx.x;     // 0..63
    const int tid  = threadIdx.x;    // 0..1023
    const int wave = tid >> 6;       // 0..15
    const int lane = tid & 63;
    const int r    = lane & 31;      // local row 0..31
    const int row  = b * RPB + r;    // global row this thread accumulates
    const int k0   = wave * 128 + (lane >> 5) * 64;  // k-chunk start
    const int m0   = wave * 128 + 2 * lane;          // my 2 mailbox words

    // weights pinned (atomic loads can't be rematerialized into the loop)
    float w[64];
#pragma unroll
    for (int j = 0; j < 64; ++j)
        w[j] = __hip_atomic_load(&Whh[(size_t)row * HH + k0 + j],
                                 __ATOMIC_RELAXED, __HIP_MEMORY_SCOPE_WORKGROUP);

    const bool is_writer = (wave == 0) && (lane < 32);
    const float bias = is_writer ? bhh[b * RPB + lane] : 0.f;

    __shared__ float hs[HH];              // staged h, wave-private chunks
    __shared__ float partial[16][33];     // [k-chunk wave][row], padded

    for (int t = 0; t < TT; ++t) {
        // xp load: independent of h, issue before the poll
        float xpv = is_writer ? xp[(size_t)t * HH + b * RPB + lane] : 0.f;

        // stage MY wave's 128-float chunk (2 words/lane), wave-private
        if (t == 0) {
            float2 hv; hv.x = h0[m0]; hv.y = h0[m0 + 1];
            *(float2*)&hs[m0] = hv;
        } else {
            const unsigned int want = (unsigned int)t;
            const unsigned long long* mb = mbox + (size_t)(t & 1) * HH;
            unsigned long long v0 = __hip_atomic_load(&mb[m0],
                __ATOMIC_RELAXED, __HIP_MEMORY_SCOPE_AGENT);
            unsigned long long v1 = __hip_atomic_load(&mb[m0 + 1],
                __ATOMIC_RELAXED, __HIP_MEMORY_SCOPE_AGENT);
            while ((unsigned int)(v0 >> 32) != want)
                v0 = __hip_atomic_load(&mb[m0],
                    __ATOMIC_RELAXED, __HIP_MEMORY_SCOPE_AGENT);
            while ((unsigned int)(v1 >> 32) != want)
                v1 = __hip_atomic_load(&mb[m0 + 1],
                    __ATOMIC_RELAXED, __HIP_MEMORY_SCOPE_AGENT);
            float2 hv;
            hv.x = __uint_as_float((unsigned int)v0);
            hv.y = __uint_as_float((unsigned int)v1);
            *(float2*)&hs[m0] = hv;   // same-wave write->read: lgkmcnt only
        }

        // matvec partial: 16 broadcast ds_read_b128 + 64 FMA (own chunk)
        const float* hk = &hs[k0];
        float p = 0.f;
#pragma unroll
        for (int jj = 0; jj < 16; ++jj) {
            float4 h4 = *(const float4*)&hk[jj * 4];
            p += w[jj * 4 + 0] * h4.x + w[jj * 4 + 1] * h4.y
               + w[jj * 4 + 2] * h4.z + w[jj * 4 + 3] * h4.w;
        }
        // merge the two 64-k sub-halves of this wave (full 128-k chunk)
        p += __shfl_xor(p, 32, 64);
        if (lane < 32) partial[wave][lane] = p;
        __syncthreads();   // (B) the ONLY barrier per step

        if (wave == 0) {
            // lanes 0-31 sum partial[0..7][r], lanes 32-63 sum partial[8..15][r]
            const int gbase = (lane >> 5) * 8;
            float s = 0.f;
#pragma unroll
            for (int g = 0; g < 8; ++g) s += partial[gbase + g][r];
            s += __shfl_xor(s, 32, 64);
            if (lane < 32) {
                float hv = tanhf(xpv + bias + s);
                outs[(size_t)t * HH + row] = hv;   // plain cached store
                unsigned long long pk =
                    ((unsigned long long)(unsigned int)(t + 1) << 32) |
                    (unsigned long long)__float_as_uint(hv);
                // single-instruction 256B publish (all 32 lanes, contiguous)
                __hip_atomic_store(&mbox[(size_t)((t + 1) & 1) * HH + row], pk,
                                   __ATOMIC_RELAXED, __HIP_MEMORY_SCOPE_AGENT);
            }
        }
        // no other barrier: partial[w] overwrite for t+1 is gated by wave w's
        // t+1 poll, which requires this block's wave-0 publish (after reads).
    }
}

// ---------------------------------------------------------------------------
extern "C" void kernel_launch(void* const* d_in, const int* in_sizes, int n_in,
                              void* d_out, int out_size, void* d_ws, size_t ws_size,
                              hipStream_t stream)
{
    const float* x     = (const float*)d_in[0];  // (T,1,H)
    const float* W_ih  = (const float*)d_in[1];  // (H,H)
    const float* W_hh  = (const float*)d_in[2];  // (H,H)
    const float* b_ih  = (const float*)d_in[3];  // (H)
    const float* b_hh  = (const float*)d_in[4];  // (H)
    const float* W_lin = (const float*)d_in[5];  // (O,H)
    const float* b_lin = (const float*)d_in[6];  // (O)
    const float* h0    = (const float*)d_in[7];  // (1,1,H)
    float* out = (float*)d_out;                  // (T,1,O)

    char* ws = (char*)d_ws;
    float* xp    = (float*)ws;                                       // 32 MB
    float* outs  = (float*)(ws + (size_t)TT * HH * 4);               // 32 MB
    unsigned long long* mbox =
        (unsigned long long*)(ws + 2 * (size_t)TT * HH * 4);         // 32 KB

    // no mailbox init needed: t==0 reads h0 directly; poisoned tag
    // 0xAAAAAAAA never equals a wanted tag (t < 4096).

    // Phase 1: xp = x @ W_ih^T + b_ih
    gemm_nt_bias<<<dim3(TT / 128, HH / 128), 256, 0, stream>>>(
        x, W_ih, b_ih, xp, TT, HH, HH);

    // Phase 2: sequential scan (persistent, 64 co-resident blocks)
    rnn_scan<<<NB, 1024, 0, stream>>>(xp, W_hh, b_hh, h0, outs, mbox);

    // Phase 3: out = outs @ W_lin^T + b_lin
    gemm_nt_bias<<<dim3(TT / 128, OO / 128), 256, 0, stream>>>(
        outs, W_lin, b_lin, out, TT, OO, HH);
}

// Round 7
// 8341.743 us; speedup vs baseline: 1.6880x; 1.0150x over previous
//
#include <hip/hip_runtime.h>
#include <math.h>

// Problem constants (Elman RNN)
#define TT 4096
#define HH 2048
#define OO 512

#define NB  128   // scan blocks (128 CUs active)
#define RPB 16    // rows per block = HH/NB

// ---------------------------------------------------------------------------
// Phase 1 & 3: fp32 NT GEMM  C[m,n] = sum_k A[m,k]*B[n,k] + bias[n]
// 128x128 tile, 256 threads, 8x8 per thread, BK=8. (unchanged)
// ---------------------------------------------------------------------------
__global__ __launch_bounds__(256) void gemm_nt_bias(
    const float* __restrict__ A, const float* __restrict__ B,
    const float* __restrict__ bias, float* __restrict__ C,
    int M, int N, int K)
{
    __shared__ float As[8][128];
    __shared__ float Bs[8][128];

    const int tid = threadIdx.x;
    const int bm = blockIdx.x * 128;
    const int bn = blockIdx.y * 128;

    const int lrow = tid >> 1;
    const int lk   = (tid & 1) * 4;

    const int ty = tid >> 4;
    const int tx = tid & 15;

    float acc[8][8];
#pragma unroll
    for (int i = 0; i < 8; i++)
#pragma unroll
        for (int j = 0; j < 8; j++) acc[i][j] = 0.f;

    for (int k0 = 0; k0 < K; k0 += 8) {
        float4 av = *(const float4*)&A[(size_t)(bm + lrow) * K + k0 + lk];
        float4 bv = *(const float4*)&B[(size_t)(bn + lrow) * K + k0 + lk];
        __syncthreads();
        As[lk + 0][lrow] = av.x; As[lk + 1][lrow] = av.y;
        As[lk + 2][lrow] = av.z; As[lk + 3][lrow] = av.w;
        Bs[lk + 0][lrow] = bv.x; Bs[lk + 1][lrow] = bv.y;
        Bs[lk + 2][lrow] = bv.z; Bs[lk + 3][lrow] = bv.w;
        __syncthreads();
#pragma unroll
        for (int kk = 0; kk < 8; kk++) {
            float a[8], b[8];
            *(float4*)&a[0] = *(const float4*)&As[kk][ty * 4];
            *(float4*)&a[4] = *(const float4*)&As[kk][64 + ty * 4];
            *(float4*)&b[0] = *(const float4*)&Bs[kk][tx * 4];
            *(float4*)&b[4] = *(const float4*)&Bs[kk][64 + tx * 4];
#pragma unroll
            for (int i = 0; i < 8; i++)
#pragma unroll
                for (int j = 0; j < 8; j++)
                    acc[i][j] += a[i] * b[j];
        }
    }

#pragma unroll
    for (int g = 0; g < 2; g++) {
        const int n = bn + g * 64 + tx * 4;
        float4 bv = *(const float4*)&bias[n];
#pragma unroll
        for (int i = 0; i < 8; i++) {
            const int m = bm + ((i < 4) ? (ty * 4 + i) : (64 + ty * 4 + (i - 4)));
            float4 cv;
            cv.x = acc[i][g * 4 + 0] + bv.x;
            cv.y = acc[i][g * 4 + 1] + bv.y;
            cv.z = acc[i][g * 4 + 2] + bv.z;
            cv.w = acc[i][g * 4 + 3] + bv.w;
            *(float4*)&C[(size_t)m * N + n] = cv;
        }
    }
}

// ---------------------------------------------------------------------------
// Phase 2: persistent scan, 128 blocks x 1024 threads, block owns 16 rows.
//
// R7 (vs R6): halve per-CU work by doubling scan blocks (64->128, rows/block
// 32->16). R6's step budget showed ~1000 cyc/step of per-CU LDS-pipe
// serialization (256 ds_read_b128 x 4 cyc); now 128 x 4 = 512 cyc, and VALU
// halves too. Poll loads combined into ONE retry loop (R6's serial loops
// left v1 stale -> occasional extra RT). Everything else = validated R6
// structure: wave-private staging (no stage barrier), single barrier (B),
// wave-0 single-instruction contiguous publish, tagged double-buffered mbox.
//
// Thread map: wave w (0..15) covers k-chunk [w*128,(w+1)*128).
//   lane: r = lane&15 -> local row; q = lane>>4 (0..3) -> 32-k subchunk.
//   w[32]/thread pinned via atomic-load trick (lives in unified VGPR/AGPR).
// Partials: partial[w][q*17+r] (pad 17 breaks power-of-2 strides).
// Reduce: wave 0, lane l: row=l&15, qq=l>>4: 16 serial LDS reads over w,
//   then shfl_xor(16), shfl_xor(32) fold qq -> lanes 0-15 publish 128B.
// ---------------------------------------------------------------------------
__global__ __launch_bounds__(1024, 4) void rnn_scan(
    const float* __restrict__ xp,    // (T,H) input projection incl. b_ih
    const float* __restrict__ Whh,   // (H,H)
    const float* __restrict__ bhh,   // (H)
    const float* __restrict__ h0,    // (H)
    float* __restrict__ outs,        // (T,H) hidden states out
    unsigned long long* __restrict__ mbox)  // [2][HH] tagged-h mailbox
{
    const int b    = blockIdx.x;     // 0..127
    const int tid  = threadIdx.x;    // 0..1023
    const int wave = tid >> 6;       // 0..15
    const int lane = tid & 63;
    const int r    = lane & 15;      // local row 0..15
    const int q    = lane >> 4;      // 0..3: 32-k subchunk within wave chunk
    const int row  = b * RPB + r;    // global row this thread accumulates
    const int k0   = wave * 128 + q * 32;   // k-range start (32 wide)
    const int m0   = wave * 128 + 2 * lane; // my 2 mailbox words

    // weights pinned (atomic loads can't be rematerialized into the loop)
    float w[32];
#pragma unroll
    for (int j = 0; j < 32; ++j)
        w[j] = __hip_atomic_load(&Whh[(size_t)row * HH + k0 + j],
                                 __ATOMIC_RELAXED, __HIP_MEMORY_SCOPE_WORKGROUP);

    const bool is_writer = (wave == 0) && (lane < RPB);
    const float bias = is_writer ? bhh[b * RPB + lane] : 0.f;

    __shared__ float hs[HH];               // staged h, wave-private chunks
    __shared__ float partial[16][68];      // [k-chunk wave][q*17 + r]

    for (int t = 0; t < TT; ++t) {
        // xp load: independent of h, issue before the poll
        float xpv = is_writer ? xp[(size_t)t * HH + b * RPB + lane] : 0.f;

        // stage MY wave's 128-float chunk (2 words/lane), wave-private
        if (t == 0) {
            float2 hv; hv.x = h0[m0]; hv.y = h0[m0 + 1];
            *(float2*)&hs[m0] = hv;
        } else {
            const unsigned int want = (unsigned int)t;
            const unsigned long long* mb = mbox + (size_t)(t & 1) * HH;
            unsigned long long v0, v1;
            do {  // both loads in flight each retry -> one RT covers both
                v0 = __hip_atomic_load(&mb[m0],
                    __ATOMIC_RELAXED, __HIP_MEMORY_SCOPE_AGENT);
                v1 = __hip_atomic_load(&mb[m0 + 1],
                    __ATOMIC_RELAXED, __HIP_MEMORY_SCOPE_AGENT);
            } while ((((unsigned int)(v0 >> 32)) != want) |
                     (((unsigned int)(v1 >> 32)) != want));
            float2 hv;
            hv.x = __uint_as_float((unsigned int)v0);
            hv.y = __uint_as_float((unsigned int)v1);
            *(float2*)&hs[m0] = hv;   // same-wave write->read: lgkmcnt only
        }

        // matvec partial: 8 broadcast ds_read_b128 + 32 FMA (own 32-k slice)
        const float* hk = &hs[k0];
        float p = 0.f;
#pragma unroll
        for (int jj = 0; jj < 8; ++jj) {
            float4 h4 = *(const float4*)&hk[jj * 4];
            p += w[jj * 4 + 0] * h4.x + w[jj * 4 + 1] * h4.y
               + w[jj * 4 + 2] * h4.z + w[jj * 4 + 3] * h4.w;
        }
        partial[wave][q * 17 + r] = p;
        __syncthreads();   // (B) the ONLY barrier per step

        if (wave == 0) {
            // lane l: row = l&15, qq = l>>4; sum over the 16 k-chunk waves
            const int idx = (lane >> 4) * 17 + (lane & 15);
            float s = 0.f;
#pragma unroll
            for (int g = 0; g < 16; ++g) s += partial[g][idx];
            s += __shfl_xor(s, 16, 64);   // fold qq bit 0
            s += __shfl_xor(s, 32, 64);   // fold qq bit 1
            if (lane < RPB) {
                float hv = tanhf(xpv + bias + s);
                outs[(size_t)t * HH + b * RPB + lane] = hv;  // plain cached
                unsigned long long pk =
                    ((unsigned long long)(unsigned int)(t + 1) << 32) |
                    (unsigned long long)__float_as_uint(hv);
                // single-instruction 128B contiguous publish
                __hip_atomic_store(&mbox[(size_t)((t + 1) & 1) * HH + b * RPB + lane],
                                   pk, __ATOMIC_RELAXED, __HIP_MEMORY_SCOPE_AGENT);
            }
        }
        // no other barrier: partial[w] overwrite for t+1 is gated by wave w's
        // t+1 poll, which requires this block's wave-0 publish (after reads).
    }
}

// ---------------------------------------------------------------------------
extern "C" void kernel_launch(void* const* d_in, const int* in_sizes, int n_in,
                              void* d_out, int out_size, void* d_ws, size_t ws_size,
                              hipStream_t stream)
{
    const float* x     = (const float*)d_in[0];  // (T,1,H)
    const float* W_ih  = (const float*)d_in[1];  // (H,H)
    const float* W_hh  = (const float*)d_in[2];  // (H,H)
    const float* b_ih  = (const float*)d_in[3];  // (H)
    const float* b_hh  = (const float*)d_in[4];  // (H)
    const float* W_lin = (const float*)d_in[5];  // (O,H)
    const float* b_lin = (const float*)d_in[6];  // (O)
    const float* h0    = (const float*)d_in[7];  // (1,1,H)
    float* out = (float*)d_out;                  // (T,1,O)

    char* ws = (char*)d_ws;
    float* xp    = (float*)ws;                                       // 32 MB
    float* outs  = (float*)(ws + (size_t)TT * HH * 4);               // 32 MB
    unsigned long long* mbox =
        (unsigned long long*)(ws + 2 * (size_t)TT * HH * 4);         // 32 KB

    // no mailbox init needed: t==0 reads h0 directly; poisoned tag
    // 0xAAAAAAAA never equals a wanted tag (t < 4096).

    // Phase 1: xp = x @ W_ih^T + b_ih
    gemm_nt_bias<<<dim3(TT / 128, HH / 128), 256, 0, stream>>>(
        x, W_ih, b_ih, xp, TT, HH, HH);

    // Phase 2: sequential scan (persistent, 128 co-resident blocks)
    rnn_scan<<<NB, 1024, 0, stream>>>(xp, W_hh, b_hh, h0, outs, mbox);

    // Phase 3: out = outs @ W_lin^T + b_lin
    gemm_nt_bias<<<dim3(TT / 128, OO / 128), 256, 0, stream>>>(
        outs, W_lin, b_lin, out, TT, OO, HH);
}